// Round 8
// baseline (264.390 us; speedup 1.0000x reference)
//
#include <hip/hip_runtime.h>

// DRMM scoring kernel, round 8.
// Shapes: B=32, D=8, QL=16, DL=512, E=300, V=50000, 5 histogram bins.
// One block per (b,d) doc pair; 512 threads, T=1 doc token per lane.
// Combines (for the first time) BOTH levers that individually helped:
//   - 2 waves/SIMD (512-thr blocks, launch_bounds(512,2); R1 had this)
//   - deep reload-in-place global pipeline, now depth-15 (R4 had depth-5):
//     15 named float4 slots (60 VGPR; T=1 keeps acc at 16 so total ~100,
//     under the 128-VGPR limit for 2 waves/EU -- R5/R6 spilled because T=2's
//     32-acc baseline left no slot headroom).
// Step c consumes slot c%15 and reloads chunk c+15 into the same slot ->
// ~15 steps (~2000+ issue cyc) of latency cover, 15 loads in flight/lane.
// Per-token dot/norm summation order is bit-identical to rounds 1-7.

constexpr int Bn  = 32;
constexpr int Dn  = 8;
constexpr int QLn = 16;
constexpr int DLn = 512;
constexpr int En  = 300;

__global__ __launch_bounds__(512, 2) void drmm_score(
    const int*   __restrict__ bq,    // [B,QL]
    const int*   __restrict__ bd,    // [B,D,DL]
    const float* __restrict__ emb,   // [V,E]
    const float* __restrict__ w_g,   // [E]
    const float* __restrict__ b_g,   // [1]
    const float* __restrict__ w1,    // [5]
    const float* __restrict__ b1,    // [1]
    const float* __restrict__ w2,    // [1]
    const float* __restrict__ b2,    // [1]
    const float* __restrict__ w_o,   // [1]
    const float* __restrict__ b_o,   // [1]
    float*       __restrict__ out)   // [B*D]
{
    __shared__ __attribute__((aligned(16))) float q_lds[QLn * En]; // 19200 B
    __shared__ float pn_s[QLn][17];
    __shared__ float pg_s[QLn][17];
    __shared__ float qn_s[QLn];
    __shared__ float gate_s[QLn];
    __shared__ float tw_s[QLn];
    __shared__ unsigned long long hist_s[QLn]; // 5 x 12-bit packed counters per q
    __shared__ float wsum_s[QLn];

    const int n   = blockIdx.x;   // 0..255  (b*8 + d)
    const int b   = n >> 3;
    const int tid = threadIdx.x;  // 0..511

    // ---- Phase 1: stage query embeddings into LDS (float4 granularity) ----
    for (int idx = tid; idx < QLn * (En / 4); idx += 512) {   // 1200 float4s
        const int  q   = idx / (En / 4);
        const int  c   = idx - q * (En / 4);
        const long tok = bq[b * QLn + q];
        *reinterpret_cast<float4*>(&q_lds[q * En + c * 4]) =
            *reinterpret_cast<const float4*>(emb + tok * (long)En + c * 4);
    }
    if (tid < QLn) hist_s[tid] = 0ull;
    __syncthreads();

    // ---- Phase 2: query norms + gate logits (16 threads per q) ----
    if (tid < 256) {
        const int q = tid >> 4, j = tid & 15;
        float pn = 0.f, pg = 0.f;
        for (int e = j; e < En; e += 16) {
            const float v = q_lds[q * En + e];
            pn = fmaf(v, v, pn);
            pg = fmaf(v, w_g[e], pg);
        }
        pn_s[q][j] = pn;
        pg_s[q][j] = pg;
    }
    __syncthreads();
    if (tid < QLn) {
        float sn = 0.f, sg = 0.f;
        for (int j = 0; j < 16; ++j) { sn += pn_s[tid][j]; sg += pg_s[tid][j]; }
        qn_s[tid]   = sqrtf(sn);
        gate_s[tid] = sg + b_g[0];
    }
    __syncthreads();
    if (tid == 0) {
        float m = gate_s[0];
        for (int q = 1; q < QLn; ++q) m = fmaxf(m, gate_s[q]);
        float ex[QLn];
        float s = 0.f;
        for (int q = 0; q < QLn; ++q) { ex[q] = expf(gate_s[q] - m); s += ex[q]; }
        for (int q = 0; q < QLn; ++q) tw_s[q] = ex[q] / s;
    }
    __syncthreads();

    // ---- Phase 3: per-token cosine sims vs all 16 query terms ----
    const long tok = bd[n * DLn + tid];
    const float* __restrict__ r0 = emb + tok * (long)En;

    float acc[QLn];
#pragma unroll
    for (int q = 0; q < QLn; ++q) acc[q] = 0.f;
    float nrm = 0.f;

    // one 4-float chunk (order identical to rounds 1-7): norm then q0..q15
#define DRMM_CHUNK(dv, EE)                                                \
    do {                                                                  \
        nrm = fmaf((dv).x, (dv).x, nrm);                                  \
        nrm = fmaf((dv).y, (dv).y, nrm);                                  \
        nrm = fmaf((dv).z, (dv).z, nrm);                                  \
        nrm = fmaf((dv).w, (dv).w, nrm);                                  \
        _Pragma("unroll")                                                 \
        for (int q = 0; q < QLn; ++q) {                                   \
            const float4 qv =                                             \
                *reinterpret_cast<const float4*>(&q_lds[q * En + (EE)]);  \
            float a = acc[q];                                             \
            a = fmaf((dv).x, qv.x, a);                                    \
            a = fmaf((dv).y, qv.y, a);                                    \
            a = fmaf((dv).z, qv.z, a);                                    \
            a = fmaf((dv).w, qv.w, a);                                    \
            acc[q] = a;                                                   \
        }                                                                 \
    } while (0)

    // compute slot's chunk, then reload the SAME slot from 15 chunks ahead
#define DRMM_STEP_R(SA, EE)                                               \
    do {                                                                  \
        DRMM_CHUNK(SA, (EE));                                             \
        SA = *reinterpret_cast<const float4*>(r0 + (EE) + 60);            \
    } while (0)

    // prologue: 15 slots hold chunks 0..14 (15 loads in flight)
    float4 s00 = *reinterpret_cast<const float4*>(r0 +  0);
    float4 s01 = *reinterpret_cast<const float4*>(r0 +  4);
    float4 s02 = *reinterpret_cast<const float4*>(r0 +  8);
    float4 s03 = *reinterpret_cast<const float4*>(r0 + 12);
    float4 s04 = *reinterpret_cast<const float4*>(r0 + 16);
    float4 s05 = *reinterpret_cast<const float4*>(r0 + 20);
    float4 s06 = *reinterpret_cast<const float4*>(r0 + 24);
    float4 s07 = *reinterpret_cast<const float4*>(r0 + 28);
    float4 s08 = *reinterpret_cast<const float4*>(r0 + 32);
    float4 s09 = *reinterpret_cast<const float4*>(r0 + 36);
    float4 s10 = *reinterpret_cast<const float4*>(r0 + 40);
    float4 s11 = *reinterpret_cast<const float4*>(r0 + 44);
    float4 s12 = *reinterpret_cast<const float4*>(r0 + 48);
    float4 s13 = *reinterpret_cast<const float4*>(r0 + 52);
    float4 s14 = *reinterpret_cast<const float4*>(r0 + 56);

#pragma unroll 1
    for (int k = 0; k < 4; ++k) {           // chunks 0..59, reload 15..74
        const int e = k * 60;
        DRMM_STEP_R(s00, e +  0);
        DRMM_STEP_R(s01, e +  4);
        DRMM_STEP_R(s02, e +  8);
        DRMM_STEP_R(s03, e + 12);
        DRMM_STEP_R(s04, e + 16);
        DRMM_STEP_R(s05, e + 20);
        DRMM_STEP_R(s06, e + 24);
        DRMM_STEP_R(s07, e + 28);
        DRMM_STEP_R(s08, e + 32);
        DRMM_STEP_R(s09, e + 36);
        DRMM_STEP_R(s10, e + 40);
        DRMM_STEP_R(s11, e + 44);
        DRMM_STEP_R(s12, e + 48);
        DRMM_STEP_R(s13, e + 52);
        DRMM_STEP_R(s14, e + 56);
    }
    // epilogue: chunks 60..74, no reload
    DRMM_CHUNK(s00, 240);
    DRMM_CHUNK(s01, 244);
    DRMM_CHUNK(s02, 248);
    DRMM_CHUNK(s03, 252);
    DRMM_CHUNK(s04, 256);
    DRMM_CHUNK(s05, 260);
    DRMM_CHUNK(s06, 264);
    DRMM_CHUNK(s07, 268);
    DRMM_CHUNK(s08, 272);
    DRMM_CHUNK(s09, 276);
    DRMM_CHUNK(s10, 280);
    DRMM_CHUNK(s11, 284);
    DRMM_CHUNK(s12, 288);
    DRMM_CHUNK(s13, 292);
    DRMM_CHUNK(s14, 296);
#undef DRMM_STEP_R
#undef DRMM_CHUNK

    const float dn = sqrtf(nrm);
    unsigned long long cnt[QLn];
#pragma unroll
    for (int q = 0; q < QLn; ++q) {
        const float denom = fmaxf(qn_s[q] * dn, 1e-8f);
        const float c     = acc[q] / denom;
        // numpy.histogram semantics with edges [-1,-0.5,0,0.5,1,1]:
        // first 4 bins half-open [lo,hi), last bin closed [1.0,1.0].
        int bin = -1;
        if      (c >= -1.0f && c < -0.5f) bin = 0;
        else if (c >= -0.5f && c <  0.0f) bin = 1;
        else if (c >=  0.0f && c <  0.5f) bin = 2;
        else if (c >=  0.5f && c <  1.0f) bin = 3;
        else if (c ==  1.0f)              bin = 4;
        cnt[q] = (bin >= 0) ? (1ull << (12 * bin)) : 0ull;
    }

    // wave reduce the packed counters, then one LDS atomic per wave per q
    const int lane = tid & 63;
#pragma unroll
    for (int q = 0; q < QLn; ++q) {
        unsigned long long v = cnt[q];
        for (int off = 32; off > 0; off >>= 1) v += __shfl_down(v, off, 64);
        if (lane == 0) atomicAdd(&hist_s[q], v);
    }
    __syncthreads();

    // ---- Phase 4: ffnn + gated sum -> score ----
    if (tid < QLn) {
        const unsigned long long h = hist_s[tid];
        float f = 0.f;
        f = fmaf((float)((h >>  0) & 0xFFFull), w1[0], f);
        f = fmaf((float)((h >> 12) & 0xFFFull), w1[1], f);
        f = fmaf((float)((h >> 24) & 0xFFFull), w1[2], f);
        f = fmaf((float)((h >> 36) & 0xFFFull), w1[3], f);
        f = fmaf((float)((h >> 48) & 0xFFFull), w1[4], f);
        f += b1[0];
        f = f * w2[0] + b2[0];
        wsum_s[tid] = f * tw_s[tid];
    }
    __syncthreads();
    if (tid == 0) {
        float s = 0.f;
        for (int q = 0; q < QLn; ++q) s += wsum_s[q];
        out[n] = s * w_o[0] + b_o[0];
    }
}

extern "C" void kernel_launch(void* const* d_in, const int* in_sizes, int n_in,
                              void* d_out, int out_size, void* d_ws, size_t ws_size,
                              hipStream_t stream) {
    const int*   bq  = (const int*)  d_in[0];  // batch_queries
    // d_in[1] query_len: unused by reference
    const int*   bd  = (const int*)  d_in[2];  // batch_docs
    // d_in[3] doc_len: unused by reference
    const float* emb = (const float*)d_in[4];
    const float* w_g = (const float*)d_in[5];
    const float* b_g = (const float*)d_in[6];
    const float* w1  = (const float*)d_in[7];
    const float* b1  = (const float*)d_in[8];
    const float* w2  = (const float*)d_in[9];
    const float* b2  = (const float*)d_in[10];
    const float* w_o = (const float*)d_in[11];
    const float* b_o = (const float*)d_in[12];

    drmm_score<<<Bn * Dn, 512, 0, stream>>>(
        bq, bd, emb, w_g, b_g, w1, b1, w2, b2, w_o, b_o, (float*)d_out);
}

// Round 9
// 108.146 us; speedup vs baseline: 2.4448x; 2.4448x over previous
//
#include <hip/hip_runtime.h>

// DRMM scoring kernel, round 9.
// Shapes: B=32, D=8, QL=16, DL=512, E=300, V=50000, 5 histogram bins.
// NEW: doc split across 2 blocks -> grid 512 = 2 blocks/CU = 2 waves/SIMD
// (first clean combination of R4's depth-5 reload-in-place pipeline with
// >1 wave/SIMD; R8 failed because launch_bounds(512,2) forced spill).
// Kernel A: 256 thr, T=1 token/lane, tokens [half*256, half*256+256).
//   Depth-5 reload-in-place global pipeline (R4 idiom, T=1 -> ~110-130 VGPR,
//   no launch_bounds). Partial 5x12-bit packed histograms written to d_ws
//   at [n][half][q] (single writer per slot -> no zero-init, deterministic).
//   half==0 blocks also write term weights tw[n][q].
// Kernel B: sums the two u64 partials (exact) and runs the ffnn/gate
//   epilogue in the same op order as rounds 1-8 -> bit-identical output.

constexpr int Bn  = 32;
constexpr int Dn  = 8;
constexpr int QLn = 16;
constexpr int DLn = 512;
constexpr int En  = 300;

// d_ws layout: [0, 64KB) u64 hist[256][2][16]; [64KB, 80KB) float tw[256][16]
constexpr size_t WS_HIST_U64 = 256 * 2 * 16;            // 8192 u64 = 64 KB
constexpr size_t WS_TW_OFF   = WS_HIST_U64 * 8;         // byte offset of tw

__global__ __launch_bounds__(256) void drmm_partial(
    const int*   __restrict__ bq,    // [B,QL]
    const int*   __restrict__ bd,    // [B,D,DL]
    const float* __restrict__ emb,   // [V,E]
    const float* __restrict__ w_g,   // [E]
    const float* __restrict__ b_g,   // [1]
    unsigned long long* __restrict__ ws_hist,  // [256][2][16]
    float*       __restrict__ ws_tw)           // [256][16]
{
    __shared__ __attribute__((aligned(16))) float q_lds[QLn * En]; // 19200 B
    __shared__ float pn_s[QLn][17];
    __shared__ float pg_s[QLn][17];
    __shared__ float qn_s[QLn];
    __shared__ float gate_s[QLn];
    __shared__ unsigned long long hist_s[QLn];

    const int n    = blockIdx.x >> 1;   // 0..255  (b*8 + d)
    const int half = blockIdx.x & 1;    // which 256-token half
    const int b    = n >> 3;
    const int tid  = threadIdx.x;       // 0..255

    // ---- Phase 1: stage query embeddings into LDS (float4 granularity) ----
    for (int idx = tid; idx < QLn * (En / 4); idx += 256) {   // 1200 float4s
        const int  q   = idx / (En / 4);
        const int  c   = idx - q * (En / 4);
        const long tok = bq[b * QLn + q];
        *reinterpret_cast<float4*>(&q_lds[q * En + c * 4]) =
            *reinterpret_cast<const float4*>(emb + tok * (long)En + c * 4);
    }
    if (tid < QLn) hist_s[tid] = 0ull;
    __syncthreads();

    // ---- Phase 2: query norms + gate logits (16 threads per q) ----
    {
        const int q = tid >> 4, j = tid & 15;
        float pn = 0.f, pg = 0.f;
        for (int e = j; e < En; e += 16) {
            const float v = q_lds[q * En + e];
            pn = fmaf(v, v, pn);
            pg = fmaf(v, w_g[e], pg);
        }
        pn_s[q][j] = pn;
        pg_s[q][j] = pg;
    }
    __syncthreads();
    if (tid < QLn) {
        float sn = 0.f, sg = 0.f;
        for (int j = 0; j < 16; ++j) { sn += pn_s[tid][j]; sg += pg_s[tid][j]; }
        qn_s[tid]   = sqrtf(sn);
        gate_s[tid] = sg + b_g[0];
    }
    __syncthreads();
    if (half == 0 && tid == 0) {
        // softmax over the 16 query terms (same op order as rounds 1-8)
        float m = gate_s[0];
        for (int q = 1; q < QLn; ++q) m = fmaxf(m, gate_s[q]);
        float ex[QLn];
        float s = 0.f;
        for (int q = 0; q < QLn; ++q) { ex[q] = expf(gate_s[q] - m); s += ex[q]; }
        for (int q = 0; q < QLn; ++q) ws_tw[n * QLn + q] = ex[q] / s;
    }

    // ---- Phase 3: per-token cosine sims vs all 16 query terms (T=1) ----
    const long tok = bd[n * DLn + half * 256 + tid];
    const float* __restrict__ r0 = emb + tok * (long)En;

    float acc[QLn];
#pragma unroll
    for (int q = 0; q < QLn; ++q) acc[q] = 0.f;
    float nrm = 0.f;

    // one 4-float chunk (order identical to rounds 1-8): norm then q0..q15
#define DRMM_CHUNK(dv, EE)                                                \
    do {                                                                  \
        nrm = fmaf((dv).x, (dv).x, nrm);                                  \
        nrm = fmaf((dv).y, (dv).y, nrm);                                  \
        nrm = fmaf((dv).z, (dv).z, nrm);                                  \
        nrm = fmaf((dv).w, (dv).w, nrm);                                  \
        _Pragma("unroll")                                                 \
        for (int q = 0; q < QLn; ++q) {                                   \
            const float4 qv =                                             \
                *reinterpret_cast<const float4*>(&q_lds[q * En + (EE)]);  \
            float a = acc[q];                                             \
            a = fmaf((dv).x, qv.x, a);                                    \
            a = fmaf((dv).y, qv.y, a);                                    \
            a = fmaf((dv).z, qv.z, a);                                    \
            a = fmaf((dv).w, qv.w, a);                                    \
            acc[q] = a;                                                   \
        }                                                                 \
    } while (0)

    // compute slot's chunk, then reload the SAME slot from 5 chunks ahead
#define DRMM_STEP_R(SA, EE)                                               \
    do {                                                                  \
        DRMM_CHUNK(SA, (EE));                                             \
        SA = *reinterpret_cast<const float4*>(r0 + (EE) + 20);            \
    } while (0)

    // prologue: slots hold chunks 0..4 (5 loads in flight)
    float4 sa = *reinterpret_cast<const float4*>(r0 + 0);
    float4 sb = *reinterpret_cast<const float4*>(r0 + 4);
    float4 sc = *reinterpret_cast<const float4*>(r0 + 8);
    float4 sd = *reinterpret_cast<const float4*>(r0 + 12);
    float4 se = *reinterpret_cast<const float4*>(r0 + 16);

#pragma unroll 1
    for (int k = 0; k < 14; ++k) {          // chunks 0..69, reload 5..74
        const int e = k * 20;
        DRMM_STEP_R(sa, e + 0);
        DRMM_STEP_R(sb, e + 4);
        DRMM_STEP_R(sc, e + 8);
        DRMM_STEP_R(sd, e + 12);
        DRMM_STEP_R(se, e + 16);
    }
    // epilogue: chunks 70..74, no reload
    DRMM_CHUNK(sa, 280);
    DRMM_CHUNK(sb, 284);
    DRMM_CHUNK(sc, 288);
    DRMM_CHUNK(sd, 292);
    DRMM_CHUNK(se, 296);
#undef DRMM_STEP_R
#undef DRMM_CHUNK

    const float dn = sqrtf(nrm);
    unsigned long long cnt[QLn];
#pragma unroll
    for (int q = 0; q < QLn; ++q) {
        const float denom = fmaxf(qn_s[q] * dn, 1e-8f);
        const float c     = acc[q] / denom;
        // numpy.histogram semantics with edges [-1,-0.5,0,0.5,1,1]:
        // first 4 bins half-open [lo,hi), last bin closed [1.0,1.0].
        int bin = -1;
        if      (c >= -1.0f && c < -0.5f) bin = 0;
        else if (c >= -0.5f && c <  0.0f) bin = 1;
        else if (c >=  0.0f && c <  0.5f) bin = 2;
        else if (c >=  0.5f && c <  1.0f) bin = 3;
        else if (c ==  1.0f)              bin = 4;
        cnt[q] = (bin >= 0) ? (1ull << (12 * bin)) : 0ull;
    }

    // wave reduce the packed counters, then one LDS atomic per wave per q
    const int lane = tid & 63;
#pragma unroll
    for (int q = 0; q < QLn; ++q) {
        unsigned long long v = cnt[q];
        for (int off = 32; off > 0; off >>= 1) v += __shfl_down(v, off, 64);
        if (lane == 0) atomicAdd(&hist_s[q], v);
    }
    __syncthreads();

    // write this block's partial histogram (single writer per slot)
    if (tid < QLn) ws_hist[(n * 2 + half) * QLn + tid] = hist_s[tid];
}

__global__ __launch_bounds__(64) void drmm_final(
    const unsigned long long* __restrict__ ws_hist,  // [256][2][16]
    const float* __restrict__ ws_tw,                 // [256][16]
    const float* __restrict__ w1,    // [5]
    const float* __restrict__ b1,    // [1]
    const float* __restrict__ w2,    // [1]
    const float* __restrict__ b2,    // [1]
    const float* __restrict__ w_o,   // [1]
    const float* __restrict__ b_o,   // [1]
    float*       __restrict__ out)   // [B*D]
{
    const int n = blockIdx.x * 64 + threadIdx.x;     // 0..255
    float s = 0.f;
    for (int q = 0; q < QLn; ++q) {
        const unsigned long long h =
            ws_hist[(n * 2 + 0) * QLn + q] + ws_hist[(n * 2 + 1) * QLn + q];
        float f = 0.f;
        f = fmaf((float)((h >>  0) & 0xFFFull), w1[0], f);
        f = fmaf((float)((h >> 12) & 0xFFFull), w1[1], f);
        f = fmaf((float)((h >> 24) & 0xFFFull), w1[2], f);
        f = fmaf((float)((h >> 36) & 0xFFFull), w1[3], f);
        f = fmaf((float)((h >> 48) & 0xFFFull), w1[4], f);
        f += b1[0];
        f = f * w2[0] + b2[0];
        s += f * ws_tw[n * QLn + q];
    }
    out[n] = s * w_o[0] + b_o[0];
}

extern "C" void kernel_launch(void* const* d_in, const int* in_sizes, int n_in,
                              void* d_out, int out_size, void* d_ws, size_t ws_size,
                              hipStream_t stream) {
    const int*   bq  = (const int*)  d_in[0];  // batch_queries
    // d_in[1] query_len: unused by reference
    const int*   bd  = (const int*)  d_in[2];  // batch_docs
    // d_in[3] doc_len: unused by reference
    const float* emb = (const float*)d_in[4];
    const float* w_g = (const float*)d_in[5];
    const float* b_g = (const float*)d_in[6];
    const float* w1  = (const float*)d_in[7];
    const float* b1  = (const float*)d_in[8];
    const float* w2  = (const float*)d_in[9];
    const float* b2  = (const float*)d_in[10];
    const float* w_o = (const float*)d_in[11];
    const float* b_o = (const float*)d_in[12];

    unsigned long long* ws_hist = (unsigned long long*)d_ws;
    float*              ws_tw   = (float*)((char*)d_ws + WS_TW_OFF);

    drmm_partial<<<Bn * Dn * 2, 256, 0, stream>>>(
        bq, bd, emb, w_g, b_g, ws_hist, ws_tw);
    drmm_final<<<4, 64, 0, stream>>>(
        ws_hist, ws_tw, w1, b1, w2, b2, w_o, b_o, (float*)d_out);
}

// Round 10
// 75.761 us; speedup vs baseline: 3.4898x; 1.4275x over previous
//
#include <hip/hip_runtime.h>

// DRMM scoring kernel, round 10.
// Shapes: B=32, D=8, QL=16, DL=512, E=300, V=50000, 5 histogram bins.
// One block per (b,d) doc pair; 256 threads, T=2 doc tokens per lane.
// CANONICAL STAGE->BARRIER->COMPUTE (guide §5 / T14), E-tiled:
//   300 floats = 15 phases x 20 floats. Per phase, each thread issues its 2
//   tokens' 80B (5 contiguous float4 per token -- MSHR-mergeable runs) into
//   registers EARLY, computes the current phase's 5 chunks from the LDS doc
//   tile (float4 at 16B lane stride = standard conflict-free pattern), then
//   writes the staged regs to the other buffer and barriers (issue-early /
//   write-late). One vmcnt wait per PHASE instead of two per chunk-step --
//   the whole phase (~1360 cyc of FMAs) covers the scattered-gather latency
//   that R1-R9 paid per step (~2000 cyc/step measured in R4).
// DRMM_CHUNK is R4's macro fed identical values in identical order ->
// per-token dot/norm summation is bit-identical to rounds 1-9 (passing).

constexpr int Bn  = 32;
constexpr int Dn  = 8;
constexpr int QLn = 16;
constexpr int DLn = 512;
constexpr int En  = 300;
constexpr int PH  = 20;   // floats per phase
constexpr int NPH = 15;   // 15 * 20 = 300

__global__ __launch_bounds__(256) void drmm_score(
    const int*   __restrict__ bq,    // [B,QL]
    const int*   __restrict__ bd,    // [B,D,DL]
    const float* __restrict__ emb,   // [V,E]
    const float* __restrict__ w_g,   // [E]
    const float* __restrict__ b_g,   // [1]
    const float* __restrict__ w1,    // [5]
    const float* __restrict__ b1,    // [1]
    const float* __restrict__ w2,    // [1]
    const float* __restrict__ b2,    // [1]
    const float* __restrict__ w_o,   // [1]
    const float* __restrict__ b_o,   // [1]
    float*       __restrict__ out)   // [B*D]
{
    __shared__ __attribute__((aligned(16))) float q_lds[QLn * En]; // 19200 B
    __shared__ float4 dlds4[2][5 * DLn];       // [buf][c*512 + t], 81920 B
    __shared__ float pn_s[QLn][17];
    __shared__ float pg_s[QLn][17];
    __shared__ float qn_s[QLn];
    __shared__ float gate_s[QLn];
    __shared__ float tw_s[QLn];
    __shared__ unsigned long long hist_s[QLn]; // 5 x 12-bit packed counters per q
    __shared__ float wsum_s[QLn];

    const int n   = blockIdx.x;   // 0..255  (b*8 + d)
    const int b   = n >> 3;
    const int tid = threadIdx.x;  // 0..255

    // ---- Phase 1: stage query embeddings into LDS (float4 granularity) ----
    for (int idx = tid; idx < QLn * (En / 4); idx += 256) {   // 1200 float4s
        const int  q   = idx / (En / 4);
        const int  c   = idx - q * (En / 4);
        const long tok = bq[b * QLn + q];
        *reinterpret_cast<float4*>(&q_lds[q * En + c * 4]) =
            *reinterpret_cast<const float4*>(emb + tok * (long)En + c * 4);
    }
    if (tid < QLn) hist_s[tid] = 0ull;
    __syncthreads();

    // ---- Phase 2: query norms + gate logits (16 threads per q) ----
    {
        const int q = tid >> 4, j = tid & 15;
        float pn = 0.f, pg = 0.f;
        for (int e = j; e < En; e += 16) {
            const float v = q_lds[q * En + e];
            pn = fmaf(v, v, pn);
            pg = fmaf(v, w_g[e], pg);
        }
        pn_s[q][j] = pn;
        pg_s[q][j] = pg;
    }
    __syncthreads();
    if (tid < QLn) {
        float sn = 0.f, sg = 0.f;
        for (int j = 0; j < 16; ++j) { sn += pn_s[tid][j]; sg += pg_s[tid][j]; }
        qn_s[tid]   = sqrtf(sn);
        gate_s[tid] = sg + b_g[0];
    }
    __syncthreads();
    if (tid == 0) {
        float m = gate_s[0];
        for (int q = 1; q < QLn; ++q) m = fmaxf(m, gate_s[q]);
        float ex[QLn];
        float s = 0.f;
        for (int q = 0; q < QLn; ++q) { ex[q] = expf(gate_s[q] - m); s += ex[q]; }
        for (int q = 0; q < QLn; ++q) tw_s[q] = ex[q] / s;
    }
    __syncthreads();

    // ---- Phase 3: per-token cosine sims; 2 tokens per lane, E-tiled ----
    const long tok0 = bd[n * DLn + tid];
    const long tok1 = bd[n * DLn + tid + 256];
    const float* __restrict__ r0 = emb + tok0 * (long)En;
    const float* __restrict__ r1 = emb + tok1 * (long)En;

    float acc0[QLn], acc1[QLn];
#pragma unroll
    for (int q = 0; q < QLn; ++q) { acc0[q] = 0.f; acc1[q] = 0.f; }
    float nr0 = 0.f, nr1 = 0.f;

    // R4's chunk macro, unchanged: norm xyzw then q0..q15, same chains.
#define DRMM_CHUNK(d0, d1, EE)                                            \
    do {                                                                  \
        nr0 = fmaf((d0).x, (d0).x, nr0);                                  \
        nr0 = fmaf((d0).y, (d0).y, nr0);                                  \
        nr0 = fmaf((d0).z, (d0).z, nr0);                                  \
        nr0 = fmaf((d0).w, (d0).w, nr0);                                  \
        nr1 = fmaf((d1).x, (d1).x, nr1);                                  \
        nr1 = fmaf((d1).y, (d1).y, nr1);                                  \
        nr1 = fmaf((d1).z, (d1).z, nr1);                                  \
        nr1 = fmaf((d1).w, (d1).w, nr1);                                  \
        _Pragma("unroll")                                                 \
        for (int q = 0; q < QLn; ++q) {                                   \
            const float4 qv =                                             \
                *reinterpret_cast<const float4*>(&q_lds[q * En + (EE)]);  \
            float s0 = acc0[q];                                           \
            s0 = fmaf((d0).x, qv.x, s0);                                  \
            s0 = fmaf((d0).y, qv.y, s0);                                  \
            s0 = fmaf((d0).z, qv.z, s0);                                  \
            s0 = fmaf((d0).w, qv.w, s0);                                  \
            acc0[q] = s0;                                                 \
            float s1 = acc1[q];                                           \
            s1 = fmaf((d1).x, qv.x, s1);                                  \
            s1 = fmaf((d1).y, qv.y, s1);                                  \
            s1 = fmaf((d1).z, qv.z, s1);                                  \
            s1 = fmaf((d1).w, qv.w, s1);                                  \
            acc1[q] = s1;                                                 \
        }                                                                 \
    } while (0)

    // staging registers: 2 tokens x 5 contiguous float4 (80B runs)
    float4 l00, l01, l02, l03, l04, l10, l11, l12, l13, l14;

#define STAGE_LOAD(PP)                                                    \
    do {                                                                  \
        const int eb_ = (PP) * PH;                                        \
        l00 = *reinterpret_cast<const float4*>(r0 + eb_ +  0);            \
        l01 = *reinterpret_cast<const float4*>(r0 + eb_ +  4);            \
        l02 = *reinterpret_cast<const float4*>(r0 + eb_ +  8);            \
        l03 = *reinterpret_cast<const float4*>(r0 + eb_ + 12);            \
        l04 = *reinterpret_cast<const float4*>(r0 + eb_ + 16);            \
        l10 = *reinterpret_cast<const float4*>(r1 + eb_ +  0);            \
        l11 = *reinterpret_cast<const float4*>(r1 + eb_ +  4);            \
        l12 = *reinterpret_cast<const float4*>(r1 + eb_ +  8);            \
        l13 = *reinterpret_cast<const float4*>(r1 + eb_ + 12);            \
        l14 = *reinterpret_cast<const float4*>(r1 + eb_ + 16);            \
    } while (0)

#define STAGE_WRITE(PP)                                                   \
    do {                                                                  \
        float4* dst_ = &dlds4[(PP) & 1][0];                               \
        dst_[0 * DLn + tid]       = l00;                                  \
        dst_[1 * DLn + tid]       = l01;                                  \
        dst_[2 * DLn + tid]       = l02;                                  \
        dst_[3 * DLn + tid]       = l03;                                  \
        dst_[4 * DLn + tid]       = l04;                                  \
        dst_[0 * DLn + tid + 256] = l10;                                  \
        dst_[1 * DLn + tid + 256] = l11;                                  \
        dst_[2 * DLn + tid + 256] = l12;                                  \
        dst_[3 * DLn + tid + 256] = l13;                                  \
        dst_[4 * DLn + tid + 256] = l14;                                  \
    } while (0)

#define PHASE_COMPUTE(PP)                                                 \
    do {                                                                  \
        const float4* src_ = &dlds4[(PP) & 1][0];                         \
        const int e0_ = (PP) * PH;                                        \
        { float4 d0 = src_[0 * DLn + tid], d1 = src_[0 * DLn + tid + 256];\
          DRMM_CHUNK(d0, d1, e0_ +  0); }                                 \
        { float4 d0 = src_[1 * DLn + tid], d1 = src_[1 * DLn + tid + 256];\
          DRMM_CHUNK(d0, d1, e0_ +  4); }                                 \
        { float4 d0 = src_[2 * DLn + tid], d1 = src_[2 * DLn + tid + 256];\
          DRMM_CHUNK(d0, d1, e0_ +  8); }                                 \
        { float4 d0 = src_[3 * DLn + tid], d1 = src_[3 * DLn + tid + 256];\
          DRMM_CHUNK(d0, d1, e0_ + 12); }                                 \
        { float4 d0 = src_[4 * DLn + tid], d1 = src_[4 * DLn + tid + 256];\
          DRMM_CHUNK(d0, d1, e0_ + 16); }                                 \
    } while (0)

    // prologue: stage phase 0
    STAGE_LOAD(0);
    STAGE_WRITE(0);
    __syncthreads();

#pragma unroll 1
    for (int p = 0; p < NPH - 1; ++p) {
        STAGE_LOAD(p + 1);       // issue next phase's gathers EARLY
        PHASE_COMPUTE(p);        // ~1360 cyc of FMAs covering them
        STAGE_WRITE(p + 1);      // vmcnt drain happens here, once per phase
        __syncthreads();
    }
    PHASE_COMPUTE(NPH - 1);      // final phase, no staging

#undef PHASE_COMPUTE
#undef STAGE_WRITE
#undef STAGE_LOAD
#undef DRMM_CHUNK

    const float dn0 = sqrtf(nr0);
    const float dn1 = sqrtf(nr1);

    unsigned long long cnt[QLn];
#pragma unroll
    for (int q = 0; q < QLn; ++q) {
        unsigned long long v = 0ull;
        {
            const float denom = fmaxf(qn_s[q] * dn0, 1e-8f);
            const float c     = acc0[q] / denom;
            int bin = -1;
            if      (c >= -1.0f && c < -0.5f) bin = 0;
            else if (c >= -0.5f && c <  0.0f) bin = 1;
            else if (c >=  0.0f && c <  0.5f) bin = 2;
            else if (c >=  0.5f && c <  1.0f) bin = 3;
            else if (c ==  1.0f)              bin = 4;
            if (bin >= 0) v += 1ull << (12 * bin);
        }
        {
            const float denom = fmaxf(qn_s[q] * dn1, 1e-8f);
            const float c     = acc1[q] / denom;
            int bin = -1;
            if      (c >= -1.0f && c < -0.5f) bin = 0;
            else if (c >= -0.5f && c <  0.0f) bin = 1;
            else if (c >=  0.0f && c <  0.5f) bin = 2;
            else if (c >=  0.5f && c <  1.0f) bin = 3;
            else if (c ==  1.0f)              bin = 4;
            if (bin >= 0) v += 1ull << (12 * bin);
        }
        cnt[q] = v;
    }

    const int lane = tid & 63;
#pragma unroll
    for (int q = 0; q < QLn; ++q) {
        unsigned long long v = cnt[q];
        for (int off = 32; off > 0; off >>= 1) v += __shfl_down(v, off, 64);
        if (lane == 0) atomicAdd(&hist_s[q], v);
    }
    __syncthreads();

    // ---- Phase 4: ffnn + gated sum -> score ----
    if (tid < QLn) {
        const unsigned long long h = hist_s[tid];
        float f = 0.f;
        f = fmaf((float)((h >>  0) & 0xFFFull), w1[0], f);
        f = fmaf((float)((h >> 12) & 0xFFFull), w1[1], f);
        f = fmaf((float)((h >> 24) & 0xFFFull), w1[2], f);
        f = fmaf((float)((h >> 36) & 0xFFFull), w1[3], f);
        f = fmaf((float)((h >> 48) & 0xFFFull), w1[4], f);
        f += b1[0];
        f = f * w2[0] + b2[0];
        wsum_s[tid] = f * tw_s[tid];
    }
    __syncthreads();
    if (tid == 0) {
        float s = 0.f;
        for (int q = 0; q < QLn; ++q) s += wsum_s[q];
        out[n] = s * w_o[0] + b_o[0];
    }
}

extern "C" void kernel_launch(void* const* d_in, const int* in_sizes, int n_in,
                              void* d_out, int out_size, void* d_ws, size_t ws_size,
                              hipStream_t stream) {
    const int*   bq  = (const int*)  d_in[0];  // batch_queries
    // d_in[1] query_len: unused by reference
    const int*   bd  = (const int*)  d_in[2];  // batch_docs
    // d_in[3] doc_len: unused by reference
    const float* emb = (const float*)d_in[4];
    const float* w_g = (const float*)d_in[5];
    const float* b_g = (const float*)d_in[6];
    const float* w1  = (const float*)d_in[7];
    const float* b1  = (const float*)d_in[8];
    const float* w2  = (const float*)d_in[9];
    const float* b2  = (const float*)d_in[10];
    const float* w_o = (const float*)d_in[11];
    const float* b_o = (const float*)d_in[12];

    drmm_score<<<Bn * Dn, 256, 0, stream>>>(
        bq, bd, emb, w_g, b_g, w1, b1, w2, b2, w_o, b_o, (float*)d_out);
}